// Round 7
// baseline (257.357 us; speedup 1.0000x reference)
//
#include <hip/hip_runtime.h>

// GCN_77584289234976 — round 14.
// R13 = 230us (best). mega2 top: 76us, 204MB @2.65TB/s, Mfma 22%.
// R14 theory: (a) gen's W_p stores were 64B scatters (one o per block) ->
// half-line partial writes (FETCH 51MB shows ~15MB of line-fill reads).
// Re-tile gen to 4o x 16n x 256ki per block: LDS transpose emits 256B
// chunks per (n,ks) = 2 full 128B lines, no partials. (b) aggr: pin mb
// (not b) to XCD -> 2 P panels (1MB) L2-resident; x_t streams bounded
// 134MB L3 (b-pin left 8.4MB P thrashing 4MB L2, up to 256MB L3).
// MFMA 16x16x32 bf16 layout contract (m89/m97/m120):
//   a-frag: A[m][k], m=lane&15, k=(lane>>4)*8+j
//   b-frag: B[k][n], n=lane&15, k=(lane>>4)*8+j
//   d:      D[m][n], n(col)=lane&15, m(row)=(lane>>4)*4+reg

typedef unsigned short u16;
typedef unsigned int u32;
typedef __attribute__((ext_vector_type(8))) short bf16x8;
typedef __attribute__((ext_vector_type(4))) float f32x4;
typedef const __attribute__((address_space(1))) u16* gas1;
typedef __attribute__((address_space(3))) u16* las3;

#define NN 2048
#define EE 64
#define CC 128
#define BB 32

__device__ __forceinline__ u16 f2bf(float f) {
  u32 u = __builtin_bit_cast(u32, f);
  u += 0x7fffu + ((u >> 16) & 1u);   // round-to-nearest-even
  return (u16)(u >> 16);
}

__device__ __forceinline__ f32x4 mfma16(bf16x8 a, bf16x8 b, f32x4 c) {
  return __builtin_amdgcn_mfma_f32_16x16x32_bf16(a, b, c, 0, 0, 0);
}

// ---------------- mega0: prep(512) + poolt(256) + xtrans(1024), block-ranged
__global__ __launch_bounds__(256) void k_mega0(
    const float* __restrict__ x, const float* __restrict__ ne,
    const float* __restrict__ te, const float* __restrict__ pool,
    const float* __restrict__ bias_pool, const float* __restrict__ lnw,
    const float* __restrict__ lnb,
    float* __restrict__ e, u16* __restrict__ e_bf, float* __restrict__ bias_out,
    u16* __restrict__ pool_r, u16* __restrict__ x_t, u16* __restrict__ xg_t) {
  __shared__ __align__(16) char smem[34048];
  int bid = blockIdx.x;
  int tid = threadIdx.x;
  if (bid < 512) {
    // ---- prep: 4 nodes/block, one wave per node
    float* sh = (float*)smem;             // [4][64]
    int nw = tid >> 6, d = tid & 63;
    int n = bid * 4 + nw;
    float v = ne[n * EE + d] + te[d];
    float s = v;
#pragma unroll
    for (int off = 32; off > 0; off >>= 1) s += __shfl_xor(s, off);
    float mean = s * (1.0f / 64.0f);
    float c = v - mean;
    float q = c * c;
#pragma unroll
    for (int off = 32; off > 0; off >>= 1) q += __shfl_xor(q, off);
    float inv = rsqrtf(q * (1.0f / 64.0f) + 1e-12f);
    float ev = c * inv * lnw[d] + lnb[d];
    e[n * EE + d] = ev;
    e_bf[n * EE + d] = f2bf(ev);
    sh[nw * 64 + d] = ev;
    __syncthreads();
#pragma unroll
    for (int oo = 0; oo < 2; ++oo) {
      int o = oo * 64 + d;
      float acc = 0.f;
#pragma unroll 8
      for (int dd = 0; dd < 64; ++dd) acc += sh[nw * 64 + dd] * bias_pool[dd * CC + o];
      bias_out[n * CC + o] = acc;
    }
  } else if (bid < 768) {
    // ---- poolt: pool [d][ki][o] fp32 -> pool_r [(o,ki)][d] bf16
    float* t = (float*)smem;              // [128][65]
    int ki = bid - 512;
    for (int it = 0; it < 32; ++it) {
      int idx = it * 256 + tid;
      int d = idx >> 7, o = idx & 127;
      t[o * 65 + d] = pool[d * 32768 + ki * 128 + o];
    }
    __syncthreads();
    for (int it = 0; it < 32; ++it) {
      int idx = it * 256 + tid;
      int o = idx >> 6, d = idx & 63;
      pool_r[((size_t)o * 256 + ki) * 64 + d] = f2bf(t[o * 65 + d]);
    }
  } else {
    // ---- xtrans: x -> x_t [b][c][m] bf16 and xg_t [m][b][0..128) bf16
    u16* t = (u16*)smem;                  // [128][68]
    int bx = bid - 768;
    int b = bx >> 5;
    int m0 = (bx & 31) * 64;
    for (int it = 0; it < 32; ++it) {
      int idx = it * 256 + tid;
      int m = idx >> 7, c = idx & 127;
      float v = x[((size_t)b * NN + m0 + m) * CC + c];
      t[c * 68 + m] = f2bf(v);
    }
    __syncthreads();
    for (int it = 0; it < 32; ++it) {
      int idx = it * 256 + tid;
      int c = idx >> 6, m = idx & 63;
      x_t[((size_t)b * CC + c) * NN + m0 + m] = t[c * 68 + m];
    }
    for (int it = 0; it < 16; ++it) {
      int idx = it * 256 + tid;
      int m = idx >> 6, c2 = idx & 63;
      float2 v = *(const float2*)&x[((size_t)b * NN + m0 + m) * CC + c2 * 2];
      u32 pk = (u32)f2bf(v.x) | ((u32)f2bf(v.y) << 16);
      *(u32*)&xg_t[(((size_t)(m0 + m)) * 32 + b) * 256 + c2 * 2] = pk;
    }
  }
}

// ---------------- k_Sexp: P = exp(e @ e^T) bf16 + atomic row sums.
// 64x64 tile (35KB LDS -> 4 blk/CU), 4x4 per thread, no max-sub (|S|<=64).
__global__ __launch_bounds__(256) void k_Sexp(const float* __restrict__ e,
                                              u16* __restrict__ P,
                                              float* __restrict__ rs) {
  __shared__ float er[64 * 68];
  __shared__ float ec[64 * 68];
  int n0 = (blockIdx.x >> 5) * 64, m0 = (blockIdx.x & 31) * 64;
  int tid = threadIdx.x;
  for (int it = 0; it < 16; ++it) {
    int idx = it * 256 + tid;
    int r = idx >> 6, d = idx & 63;
    er[r * 68 + d] = e[(n0 + r) * EE + d];
    ec[r * 68 + d] = e[(m0 + r) * EE + d];
  }
  __syncthreads();
  int tx = tid & 15, ty = tid >> 4;
  float acc[4][4] = {};
  for (int d4 = 0; d4 < 64; d4 += 4) {
    f32x4 av[4], bv[4];
#pragma unroll
    for (int i = 0; i < 4; ++i) av[i] = *(const f32x4*)&er[(ty + 16 * i) * 68 + d4];
#pragma unroll
    for (int j = 0; j < 4; ++j) bv[j] = *(const f32x4*)&ec[(tx + 16 * j) * 68 + d4];
#pragma unroll
    for (int i = 0; i < 4; ++i)
#pragma unroll
      for (int j = 0; j < 4; ++j) {
        acc[i][j] += av[i][0] * bv[j][0];
        acc[i][j] += av[i][1] * bv[j][1];
        acc[i][j] += av[i][2] * bv[j][2];
        acc[i][j] += av[i][3] * bv[j][3];
      }
  }
#pragma unroll
  for (int i = 0; i < 4; ++i) {
    float s = 0.f;
#pragma unroll
    for (int j = 0; j < 4; ++j) {
      float pv = __expf(acc[i][j]);
      P[(size_t)(n0 + ty + 16 * i) * NN + m0 + tx + 16 * j] = f2bf(pv);
      s += pv;
    }
#pragma unroll
    for (int off = 8; off > 0; off >>= 1) s += __shfl_xor(s, off);  // reduce over tx
    if (tx == 0) atomicAdd(&rs[n0 + ty + 16 * i], s);
  }
}

// ---------------- mega2: aggr(512 blocks, first) + gen(4096 blocks), block-ranged
__global__ __launch_bounds__(256, 4) void k_mega2(
    const u16* __restrict__ P, const u16* __restrict__ x_t,
    const float* __restrict__ rs, u16* __restrict__ xg_t,
    const u16* __restrict__ e_bf, const u16* __restrict__ pool_r,
    u16* __restrict__ W_p) {
  __shared__ __align__(16) char smem[34048];
  int tid = threadIdx.x;
  int lane = tid & 63, w = tid >> 6;
  int lm = lane & 15, lq = lane >> 4;
  if (blockIdx.x < 512) {
    // ---- aggr: x_agg[b] = (P @ x[b]) / l -> xg_t upper half.
    // bid = b*16 + mb -> bid%8 = mb%8: XCD holds 2 P panels (1MB, L2-res);
    // x_t streams bounded (134MB L3 total). XOR-swizzled staging+reads.
    u16* As = (u16*)smem;               // [128][64] linear dest (global_load_lds)
    u16* Bs = (u16*)(smem + 16384);
    int mb = blockIdx.x & 15, b = blockIdx.x >> 4;
    int n0 = mb * 128;
    int wm = w >> 1, wn = w & 1;
    f32x4 acc[4][4] = {};
    const u16* a_src = P + (size_t)n0 * NN;
    const u16* b_src = x_t + (size_t)b * CC * NN;
    for (int kc = 0; kc < NN; kc += 64) {
      __syncthreads();
#pragma unroll
      for (int ii = 0; ii < 4; ++ii) {
        int idx = ii * 256 + tid;
        int row = idx >> 3, ch = idx & 7;
        int sc = kc + ((ch ^ (row & 7)) << 3);   // pre-swizzled source col
        __builtin_amdgcn_global_load_lds((gas1)(a_src + (size_t)row * NN + sc),
                                         (las3)(As + (size_t)(ii * 256 + w * 64) * 8), 16, 0, 0);
        __builtin_amdgcn_global_load_lds((gas1)(b_src + (size_t)row * NN + sc),
                                         (las3)(Bs + (size_t)(ii * 256 + w * 64) * 8), 16, 0, 0);
      }
      __syncthreads();
#pragma unroll
      for (int kk = 0; kk < 64; kk += 32) {
        int cb = (kk >> 3) + lq;                 // 16B chunk index (unswizzled)
        bf16x8 af[4], bq[4];
#pragma unroll
        for (int i = 0; i < 4; ++i) {
          int row = wm * 64 + i * 16 + lm;
          af[i] = *(const bf16x8*)&As[row * 64 + ((cb ^ (row & 7)) << 3)];
        }
#pragma unroll
        for (int j = 0; j < 4; ++j) {
          int row = wn * 64 + j * 16 + lm;
          bq[j] = *(const bf16x8*)&Bs[row * 64 + ((cb ^ (row & 7)) << 3)];
        }
#pragma unroll
        for (int i = 0; i < 4; ++i)
#pragma unroll
          for (int j = 0; j < 4; ++j)
            acc[i][j] = mfma16(af[i], bq[j], acc[i][j]);
      }
    }
#pragma unroll
    for (int i = 0; i < 4; ++i) {
      int nr = n0 + wm * 64 + i * 16 + lq * 4;
#pragma unroll
      for (int r = 0; r < 4; ++r) {
        float sc = 1.0f / rs[nr + r];
#pragma unroll
        for (int j = 0; j < 4; ++j) {
          int c = wn * 64 + j * 16 + lm;
          xg_t[((size_t)(nr + r) * 32 + b) * 256 + 128 + c] = f2bf(acc[i][j][r] * sc);
        }
      }
    }
  } else {
    // ---- gen v2: 4 o x 16 nodes x 256 ki per block; g = og*128 + ng.
    // Wave w owns o = o0+w. LDS Tl[o][n][ki] (o-stride 4232 elems: pad 8
    // breaks the store-phase 4-way bank collision to ~2-way).
    // Store: per (n,ks) a 256B-contiguous [4o][8ki] chunk = 2 full lines.
    u16* Tl = (u16*)smem;
    int g = blockIdx.x - 512;
    int og = g >> 7, ng = g & 127;
    int o0 = og * 4, n0 = ng * 16;
    bf16x8 eB[2];
#pragma unroll
    for (int ks = 0; ks < 2; ++ks)
      eB[ks] = *(const bf16x8*)&e_bf[(n0 + lm) * EE + ks * 32 + lq * 8];
    const u16* pbase = pool_r + (size_t)(o0 + w) * 256 * 64;
#pragma unroll
    for (int ct = 0; ct < 16; ++ct) {
      const u16* ap = pbase + (ct * 16 + lm) * 64 + lq * 8;
      bf16x8 pA0 = *(const bf16x8*)ap;          // d = lq*8..
      bf16x8 pA1 = *(const bf16x8*)(ap + 32);   // d = 32+lq*8..
      f32x4 gv = {0.f, 0.f, 0.f, 0.f};
      gv = mfma16(pA0, eB[0], gv);
      gv = mfma16(pA1, eB[1], gv);
      // D: node = lm (col), ki = ct*16 + lq*4 + r (row)
      ushort4 h;
      h.x = f2bf(gv[0]); h.y = f2bf(gv[1]); h.z = f2bf(gv[2]); h.w = f2bf(gv[3]);
      *(ushort4*)&Tl[w * 4232 + lm * 264 + ct * 16 + lq * 4] = h;
    }
    __syncthreads();
    // store: W_p[n][ks][o][ki%32]; 2048 x uint4 over 8 iters.
#pragma unroll
    for (int it = 0; it < 8; ++it) {
      int idx = it * 256 + tid;
      int n = idx >> 7, rem = idx & 127;
      int ks = rem >> 4, rem2 = rem & 15;
      int o = rem2 >> 2, ki8 = rem2 & 3;
      uint4 v = *(const uint4*)&Tl[o * 4232 + n * 264 + ks * 32 + ki8 * 8];
      *(uint4*)&W_p[(size_t)(n0 + n) * 32768 + ks * 4096 + (o0 + o) * 32 + ki8 * 8] = v;
    }
  }
}

// ---------------- k_apply v2: out[b,n,o] = xg[n] @ W[n] + bias.
// W_p permuted layout -> B-frag load = (ot*16+lm)*64B + lq*16B: 16 lanes x
// 64B fully-coalesced 1KB per wave instruction.
__global__ __launch_bounds__(256, 3) void k_apply(const u16* __restrict__ xg_t,
                                                  const u16* __restrict__ W_p,
                                                  const float* __restrict__ bias,
                                                  float* __restrict__ out) {
  int n0 = blockIdx.x * 2;
  int tid = threadIdx.x;
  int lane = tid & 63, w = tid >> 6;
  int lm = lane & 15, lq = lane >> 4;
  int n = n0 + (w & 1), oh = w >> 1;    // node, o-half(64)
  const u16* xb = xg_t + (size_t)n * 32 * 256;
  const u16* wb = W_p + (size_t)n * 32768 + (size_t)oh * 64 * 32;
  f32x4 acc[2][4] = {};
#pragma unroll
  for (int ks = 0; ks < 8; ++ks) {
    int ko = ks * 32 + lq * 8;
    bf16x8 a0 = *(const bf16x8*)&xb[lm * 256 + ko];
    bf16x8 a1 = *(const bf16x8*)&xb[(16 + lm) * 256 + ko];
#pragma unroll
    for (int ot = 0; ot < 4; ++ot) {
      bf16x8 bv = *(const bf16x8*)&wb[(size_t)ks * 4096 + (ot * 16 + lm) * 32 + lq * 8];
      acc[0][ot] = mfma16(a0, bv, acc[0][ot]);
      acc[1][ot] = mfma16(a1, bv, acc[1][ot]);
    }
  }
#pragma unroll
  for (int ot = 0; ot < 4; ++ot) {
    int oc = oh * 64 + ot * 16 + lm;
    float bv = bias[n * CC + oc];
#pragma unroll
    for (int mt = 0; mt < 2; ++mt)
#pragma unroll
      for (int r = 0; r < 4; ++r) {
        int b = mt * 16 + lq * 4 + r;
        out[((size_t)b * NN + n) * CC + oc] = acc[mt][ot][r] + bv;
      }
  }
}

extern "C" void kernel_launch(void* const* d_in, const int* in_sizes, int n_in,
                              void* d_out, int out_size, void* d_ws, size_t ws_size,
                              hipStream_t stream) {
  const float* x        = (const float*)d_in[0];
  const float* node_emb = (const float*)d_in[1];
  const float* time_emb = (const float*)d_in[2];
  const float* pool     = (const float*)d_in[3];
  const float* bias_pl  = (const float*)d_in[4];
  const float* ln_w     = (const float*)d_in[5];
  const float* ln_b     = (const float*)d_in[6];
  float* out = (float*)d_out;

  char* p = (char*)d_ws;
  auto alloc = [&](size_t bytes) {
    char* r = p;
    p += (bytes + 255) & ~(size_t)255;
    return r;
  };
  float* e      = (float*)alloc((size_t)NN * EE * 4);
  u16*   e_bf   = (u16*)  alloc((size_t)NN * EE * 2);
  float* biasb  = (float*)alloc((size_t)NN * CC * 4);
  u16*   Pm     = (u16*)  alloc((size_t)NN * NN * 2);          // exp(S), unnormalized
  float* rs     = (float*)alloc((size_t)NN * 4);               // row sums
  u16*   x_t    = (u16*)  alloc((size_t)BB * CC * NN * 2);
  u16*   xg_t   = (u16*)  alloc((size_t)NN * BB * 256 * 2);    // [node][batch][x||xagg]
  u16*   pool_r = (u16*)  alloc((size_t)128 * 256 * 64 * 2);
  u16*   W_p    = (u16*)  alloc((size_t)NN * 32768 * 2);       // 128 MB, permuted

  if (ws_size < (size_t)(p - (char*)d_ws)) return;

  (void)hipMemsetAsync(rs, 0, (size_t)NN * 4, stream);

  k_mega0<<<1792, 256, 0, stream>>>(x, node_emb, time_emb, pool, bias_pl, ln_w, ln_b,
                                    e, e_bf, biasb, pool_r, x_t, xg_t);
  k_Sexp<<<1024, 256, 0, stream>>>(e, Pm, rs);
  k_mega2<<<4608, 256, 0, stream>>>(Pm, x_t, rs, xg_t, e_bf, pool_r, W_p);
  k_apply<<<NN / 2, 256, 0, stream>>>(xg_t, W_p, biasb, out);
}

// Round 9
// 251.500 us; speedup vs baseline: 1.0233x; 1.0233x over previous
//
#include <hip/hip_runtime.h>

// GCN_77584289234976 — round 16 (= R15 resubmit; R15 bench was an infra
// failure: "container failed twice", no counters produced).
// R14 post-mortem: regression was gen v2 alone (aggr map was identical to
// R13 despite the comment) — it un-pinned o from the XCD (R9 failure
// repeated: pool_r 4.2MB thrashing 4MB L2, FETCH +35MB) and doubled LDS
// store-phase bank conflicts. R15/R16 = R13 + two surgical deltas:
// (1) gen v3: 2o x 32n x 256ki, g = nb*64+og -> XCD = og%8 (o-pin KEPT,
//     512KB pool_r/XCD L2-resident); store chunk per (n,ks) = [2o][32ki]
//     = 128B full line (R13: 64B half-lines -> line-fill reads ~15-20MB).
// (2) mega0/xtrans reads x ONCE: xg_t lower half packed in pass 1 via
//     __shfl_xor bf16-pairing, even-c lanes store u32 (-33.5MB reads).
// MFMA 16x16x32 bf16 layout contract (m89/m97/m120):
//   a-frag: A[m][k], m=lane&15, k=(lane>>4)*8+j
//   b-frag: B[k][n], n=lane&15, k=(lane>>4)*8+j
//   d:      D[m][n], n(col)=lane&15, m(row)=(lane>>4)*4+reg

typedef unsigned short u16;
typedef unsigned int u32;
typedef __attribute__((ext_vector_type(8))) short bf16x8;
typedef __attribute__((ext_vector_type(4))) float f32x4;
typedef const __attribute__((address_space(1))) u16* gas1;
typedef __attribute__((address_space(3))) u16* las3;

#define NN 2048
#define EE 64
#define CC 128
#define BB 32

__device__ __forceinline__ u16 f2bf(float f) {
  u32 u = __builtin_bit_cast(u32, f);
  u += 0x7fffu + ((u >> 16) & 1u);   // round-to-nearest-even
  return (u16)(u >> 16);
}

__device__ __forceinline__ f32x4 mfma16(bf16x8 a, bf16x8 b, f32x4 c) {
  return __builtin_amdgcn_mfma_f32_16x16x32_bf16(a, b, c, 0, 0, 0);
}

// ---------------- mega0: prep(512) + poolt(256) + xtrans(1024), block-ranged
__global__ __launch_bounds__(256) void k_mega0(
    const float* __restrict__ x, const float* __restrict__ ne,
    const float* __restrict__ te, const float* __restrict__ pool,
    const float* __restrict__ bias_pool, const float* __restrict__ lnw,
    const float* __restrict__ lnb,
    float* __restrict__ e, u16* __restrict__ e_bf, float* __restrict__ bias_out,
    u16* __restrict__ pool_r, u16* __restrict__ x_t, u16* __restrict__ xg_t) {
  __shared__ __align__(16) char smem[34048];
  int bid = blockIdx.x;
  int tid = threadIdx.x;
  if (bid < 512) {
    // ---- prep: 4 nodes/block, one wave per node
    float* sh = (float*)smem;             // [4][64]
    int nw = tid >> 6, d = tid & 63;
    int n = bid * 4 + nw;
    float v = ne[n * EE + d] + te[d];
    float s = v;
#pragma unroll
    for (int off = 32; off > 0; off >>= 1) s += __shfl_xor(s, off);
    float mean = s * (1.0f / 64.0f);
    float c = v - mean;
    float q = c * c;
#pragma unroll
    for (int off = 32; off > 0; off >>= 1) q += __shfl_xor(q, off);
    float inv = rsqrtf(q * (1.0f / 64.0f) + 1e-12f);
    float ev = c * inv * lnw[d] + lnb[d];
    e[n * EE + d] = ev;
    e_bf[n * EE + d] = f2bf(ev);
    sh[nw * 64 + d] = ev;
    __syncthreads();
#pragma unroll
    for (int oo = 0; oo < 2; ++oo) {
      int o = oo * 64 + d;
      float acc = 0.f;
#pragma unroll 8
      for (int dd = 0; dd < 64; ++dd) acc += sh[nw * 64 + dd] * bias_pool[dd * CC + o];
      bias_out[n * CC + o] = acc;
    }
  } else if (bid < 768) {
    // ---- poolt: pool [d][ki][o] fp32 -> pool_r [(o,ki)][d] bf16
    float* t = (float*)smem;              // [128][65]
    int ki = bid - 512;
    for (int it = 0; it < 32; ++it) {
      int idx = it * 256 + tid;
      int d = idx >> 7, o = idx & 127;
      t[o * 65 + d] = pool[d * 32768 + ki * 128 + o];
    }
    __syncthreads();
    for (int it = 0; it < 32; ++it) {
      int idx = it * 256 + tid;
      int o = idx >> 6, d = idx & 63;
      pool_r[((size_t)o * 256 + ki) * 64 + d] = f2bf(t[o * 65 + d]);
    }
  } else {
    // ---- xtrans: x read ONCE -> x_t [b][c][m] bf16 (LDS transpose) and
    // xg_t [m][b][0..128) bf16 (shfl-paired u32 stores, even-c lanes).
    u16* t = (u16*)smem;                  // [128][68]
    int bx = bid - 768;
    int b = bx >> 5;
    int m0 = (bx & 31) * 64;
    for (int it = 0; it < 32; ++it) {
      int idx = it * 256 + tid;
      int m = idx >> 7, c = idx & 127;
      float v = x[((size_t)b * NN + m0 + m) * CC + c];
      u16 bf = f2bf(v);
      t[c * 68 + m] = bf;
      int partner = __shfl_xor((int)bf, 1);
      if ((c & 1) == 0) {
        u32 pk = (u32)bf | ((u32)partner << 16);
        *(u32*)&xg_t[(((size_t)(m0 + m)) * 32 + b) * 256 + c] = pk;
      }
    }
    __syncthreads();
    for (int it = 0; it < 32; ++it) {
      int idx = it * 256 + tid;
      int c = idx >> 6, m = idx & 63;
      x_t[((size_t)b * CC + c) * NN + m0 + m] = t[c * 68 + m];
    }
  }
}

// ---------------- k_Sexp: P = exp(e @ e^T) bf16 + atomic row sums.
// 64x64 tile (35KB LDS -> 4 blk/CU), 4x4 per thread, no max-sub (|S|<=64).
__global__ __launch_bounds__(256) void k_Sexp(const float* __restrict__ e,
                                              u16* __restrict__ P,
                                              float* __restrict__ rs) {
  __shared__ float er[64 * 68];
  __shared__ float ec[64 * 68];
  int n0 = (blockIdx.x >> 5) * 64, m0 = (blockIdx.x & 31) * 64;
  int tid = threadIdx.x;
  for (int it = 0; it < 16; ++it) {
    int idx = it * 256 + tid;
    int r = idx >> 6, d = idx & 63;
    er[r * 68 + d] = e[(n0 + r) * EE + d];
    ec[r * 68 + d] = e[(m0 + r) * EE + d];
  }
  __syncthreads();
  int tx = tid & 15, ty = tid >> 4;
  float acc[4][4] = {};
  for (int d4 = 0; d4 < 64; d4 += 4) {
    f32x4 av[4], bv[4];
#pragma unroll
    for (int i = 0; i < 4; ++i) av[i] = *(const f32x4*)&er[(ty + 16 * i) * 68 + d4];
#pragma unroll
    for (int j = 0; j < 4; ++j) bv[j] = *(const f32x4*)&ec[(tx + 16 * j) * 68 + d4];
#pragma unroll
    for (int i = 0; i < 4; ++i)
#pragma unroll
      for (int j = 0; j < 4; ++j) {
        acc[i][j] += av[i][0] * bv[j][0];
        acc[i][j] += av[i][1] * bv[j][1];
        acc[i][j] += av[i][2] * bv[j][2];
        acc[i][j] += av[i][3] * bv[j][3];
      }
  }
#pragma unroll
  for (int i = 0; i < 4; ++i) {
    float s = 0.f;
#pragma unroll
    for (int j = 0; j < 4; ++j) {
      float pv = __expf(acc[i][j]);
      P[(size_t)(n0 + ty + 16 * i) * NN + m0 + tx + 16 * j] = f2bf(pv);
      s += pv;
    }
#pragma unroll
    for (int off = 8; off > 0; off >>= 1) s += __shfl_xor(s, off);  // reduce over tx
    if (tx == 0) atomicAdd(&rs[n0 + ty + 16 * i], s);
  }
}

// ---------------- mega2: aggr(512 blocks, first) + gen(4096 blocks), block-ranged
__global__ __launch_bounds__(256, 4) void k_mega2(
    const u16* __restrict__ P, const u16* __restrict__ x_t,
    const float* __restrict__ rs, u16* __restrict__ xg_t,
    const u16* __restrict__ e_bf, const u16* __restrict__ pool_r,
    u16* __restrict__ W_p) {
  __shared__ __align__(16) char smem[34048];
  int tid = threadIdx.x;
  int lane = tid & 63, w = tid >> 6;
  int lm = lane & 15, lq = lane >> 4;
  if (blockIdx.x < 512) {
    // ---- aggr (R13-identical): XOR-swizzled staging+reads, mb%8 XCD pin.
    u16* As = (u16*)smem;               // [128][64] linear dest (global_load_lds)
    u16* Bs = (u16*)(smem + 16384);
    int mb = blockIdx.x & 15, b = blockIdx.x >> 4;
    int n0 = mb * 128;
    int wm = w >> 1, wn = w & 1;
    f32x4 acc[4][4] = {};
    const u16* a_src = P + (size_t)n0 * NN;
    const u16* b_src = x_t + (size_t)b * CC * NN;
    for (int kc = 0; kc < NN; kc += 64) {
      __syncthreads();
#pragma unroll
      for (int ii = 0; ii < 4; ++ii) {
        int idx = ii * 256 + tid;
        int row = idx >> 3, ch = idx & 7;
        int sc = kc + ((ch ^ (row & 7)) << 3);   // pre-swizzled source col
        __builtin_amdgcn_global_load_lds((gas1)(a_src + (size_t)row * NN + sc),
                                         (las3)(As + (size_t)(ii * 256 + w * 64) * 8), 16, 0, 0);
        __builtin_amdgcn_global_load_lds((gas1)(b_src + (size_t)row * NN + sc),
                                         (las3)(Bs + (size_t)(ii * 256 + w * 64) * 8), 16, 0, 0);
      }
      __syncthreads();
#pragma unroll
      for (int kk = 0; kk < 64; kk += 32) {
        int cb = (kk >> 3) + lq;                 // 16B chunk index (unswizzled)
        bf16x8 af[4], bq[4];
#pragma unroll
        for (int i = 0; i < 4; ++i) {
          int row = wm * 64 + i * 16 + lm;
          af[i] = *(const bf16x8*)&As[row * 64 + ((cb ^ (row & 7)) << 3)];
        }
#pragma unroll
        for (int j = 0; j < 4; ++j) {
          int row = wn * 64 + j * 16 + lm;
          bq[j] = *(const bf16x8*)&Bs[row * 64 + ((cb ^ (row & 7)) << 3)];
        }
#pragma unroll
        for (int i = 0; i < 4; ++i)
#pragma unroll
          for (int j = 0; j < 4; ++j)
            acc[i][j] = mfma16(af[i], bq[j], acc[i][j]);
      }
    }
#pragma unroll
    for (int i = 0; i < 4; ++i) {
      int nr = n0 + wm * 64 + i * 16 + lq * 4;
#pragma unroll
      for (int r = 0; r < 4; ++r) {
        float sc = 1.0f / rs[nr + r];
#pragma unroll
        for (int j = 0; j < 4; ++j) {
          int c = wn * 64 + j * 16 + lm;
          xg_t[((size_t)(nr + r) * 32 + b) * 256 + 128 + c] = f2bf(acc[i][j][r] * sc);
        }
      }
    }
  } else {
    // ---- gen v3: 2 o x 32 nodes x 256 ki; g = nb*64 + og -> XCD = og%8
    // (o-pin: 16 o = 512KB pool_r per XCD, L2-resident, R13 invariant).
    // Wave w: o_l = w&1, ki-half = w>>1. LDS Tl[2o][32n][264ki-pad],
    // o-stride 8456 u16. Store per (n,ks): [2o][32ki] = 128B full line.
    u16* Tl = (u16*)smem;
    int g = blockIdx.x - 512;
    int og = g & 63, nb = g >> 6;
    int o0 = og * 2, n0 = nb * 32;
    int o_l = w & 1, kih = w >> 1;
    bf16x8 eB[2][2];
#pragma unroll
    for (int nt = 0; nt < 2; ++nt)
#pragma unroll
      for (int ks = 0; ks < 2; ++ks)
        eB[nt][ks] = *(const bf16x8*)&e_bf[(n0 + nt * 16 + lm) * EE + ks * 32 + lq * 8];
    const u16* pbase = pool_r + ((size_t)(o0 + o_l) * 256 + kih * 128) * 64;
#pragma unroll
    for (int ct = 0; ct < 8; ++ct) {
      const u16* ap = pbase + (ct * 16 + lm) * 64 + lq * 8;
      bf16x8 pA0 = *(const bf16x8*)ap;          // d = lq*8..
      bf16x8 pA1 = *(const bf16x8*)(ap + 32);   // d = 32+lq*8..
#pragma unroll
      for (int nt = 0; nt < 2; ++nt) {
        f32x4 gv = {0.f, 0.f, 0.f, 0.f};
        gv = mfma16(pA0, eB[nt][0], gv);
        gv = mfma16(pA1, eB[nt][1], gv);
        // D: node = lm (col), ki = kih*128 + ct*16 + lq*4 + r (row)
        ushort4 h;
        h.x = f2bf(gv[0]); h.y = f2bf(gv[1]); h.z = f2bf(gv[2]); h.w = f2bf(gv[3]);
        *(ushort4*)&Tl[o_l * 8456 + (nt * 16 + lm) * 264 + kih * 128 + ct * 16 + lq * 4] = h;
      }
    }
    __syncthreads();
    // store: W_p[n][ks][o][ki%32]; per wave: one n, 8 ks-lines of 128B.
#pragma unroll
    for (int it = 0; it < 8; ++it) {
      int idx = it * 256 + tid;
      int n = idx >> 6, rem = idx & 63;
      int ks = rem >> 3, rem2 = rem & 7;
      int o = rem2 >> 2, ki8 = rem2 & 3;
      uint4 v = *(const uint4*)&Tl[o * 8456 + n * 264 + ks * 32 + ki8 * 8];
      *(uint4*)&W_p[(size_t)(n0 + n) * 32768 + ks * 4096 + (o0 + o) * 32 + ki8 * 8] = v;
    }
  }
}

// ---------------- k_apply v2: out[b,n,o] = xg[n] @ W[n] + bias.
// W_p permuted layout -> B-frag load = (ot*16+lm)*64B + lq*16B: 16 lanes x
// 64B fully-coalesced 1KB per wave instruction.
__global__ __launch_bounds__(256, 3) void k_apply(const u16* __restrict__ xg_t,
                                                  const u16* __restrict__ W_p,
                                                  const float* __restrict__ bias,
                                                  float* __restrict__ out) {
  int n0 = blockIdx.x * 2;
  int tid = threadIdx.x;
  int lane = tid & 63, w = tid >> 6;
  int lm = lane & 15, lq = lane >> 4;
  int n = n0 + (w & 1), oh = w >> 1;    // node, o-half(64)
  const u16* xb = xg_t + (size_t)n * 32 * 256;
  const u16* wb = W_p + (size_t)n * 32768 + (size_t)oh * 64 * 32;
  f32x4 acc[2][4] = {};
#pragma unroll
  for (int ks = 0; ks < 8; ++ks) {
    int ko = ks * 32 + lq * 8;
    bf16x8 a0 = *(const bf16x8*)&xb[lm * 256 + ko];
    bf16x8 a1 = *(const bf16x8*)&xb[(16 + lm) * 256 + ko];
#pragma unroll
    for (int ot = 0; ot < 4; ++ot) {
      bf16x8 bv = *(const bf16x8*)&wb[(size_t)ks * 4096 + (ot * 16 + lm) * 32 + lq * 8];
      acc[0][ot] = mfma16(a0, bv, acc[0][ot]);
      acc[1][ot] = mfma16(a1, bv, acc[1][ot]);
    }
  }
#pragma unroll
  for (int ot = 0; ot < 4; ++ot) {
    int oc = oh * 64 + ot * 16 + lm;
    float bv = bias[n * CC + oc];
#pragma unroll
    for (int mt = 0; mt < 2; ++mt)
#pragma unroll
      for (int r = 0; r < 4; ++r) {
        int b = mt * 16 + lq * 4 + r;
        out[((size_t)b * NN + n) * CC + oc] = acc[mt][ot][r] + bv;
      }
  }
}

extern "C" void kernel_launch(void* const* d_in, const int* in_sizes, int n_in,
                              void* d_out, int out_size, void* d_ws, size_t ws_size,
                              hipStream_t stream) {
  const float* x        = (const float*)d_in[0];
  const float* node_emb = (const float*)d_in[1];
  const float* time_emb = (const float*)d_in[2];
  const float* pool     = (const float*)d_in[3];
  const float* bias_pl  = (const float*)d_in[4];
  const float* ln_w     = (const float*)d_in[5];
  const float* ln_b     = (const float*)d_in[6];
  float* out = (float*)d_out;

  char* p = (char*)d_ws;
  auto alloc = [&](size_t bytes) {
    char* r = p;
    p += (bytes + 255) & ~(size_t)255;
    return r;
  };
  float* e      = (float*)alloc((size_t)NN * EE * 4);
  u16*   e_bf   = (u16*)  alloc((size_t)NN * EE * 2);
  float* biasb  = (float*)alloc((size_t)NN * CC * 4);
  u16*   Pm     = (u16*)  alloc((size_t)NN * NN * 2);          // exp(S), unnormalized
  float* rs     = (float*)alloc((size_t)NN * 4);               // row sums
  u16*   x_t    = (u16*)  alloc((size_t)BB * CC * NN * 2);
  u16*   xg_t   = (u16*)  alloc((size_t)NN * BB * 256 * 2);    // [node][batch][x||xagg]
  u16*   pool_r = (u16*)  alloc((size_t)128 * 256 * 64 * 2);
  u16*   W_p    = (u16*)  alloc((size_t)NN * 32768 * 2);       // 128 MB, permuted

  if (ws_size < (size_t)(p - (char*)d_ws)) return;

  (void)hipMemsetAsync(rs, 0, (size_t)NN * 4, stream);

  k_mega0<<<1792, 256, 0, stream>>>(x, node_emb, time_emb, pool, bias_pl, ln_w, ln_b,
                                    e, e_bf, biasb, pool_r, x_t, xg_t);
  k_Sexp<<<1024, 256, 0, stream>>>(e, Pm, rs);
  k_mega2<<<4608, 256, 0, stream>>>(Pm, x_t, rs, xg_t, e_bf, pool_r, W_p);
  k_apply<<<NN / 2, 256, 0, stream>>>(xg_t, W_p, biasb, out);
}

// Round 10
// 249.916 us; speedup vs baseline: 1.0298x; 1.0063x over previous
//
#include <hip/hip_runtime.h>

// GCN_77584289234976 — round 17.
// R16 post-mortem: (1) the +23us total regression was mega0's fused xtrans
// (mega2 itself improved 76->74.7) -> reverted to R13 two-pass form.
// (2) gen v3 full-line stores kept (-1.3us) but FETCH rose 51->74MB: halving
// nodes/block doubled pool_r logical reads; misses come from W_p's 134MB
// write-ALLOCATE evicting pool_r/x_t/P from L2. W_p is write-once-read-never
// (in this kernel) -> non-temporal stores for all write-once streams
// (W_p, xg_t, x_t, pool_r, out) + nt loads for apply's W_p stream.
// MFMA 16x16x32 bf16 layout contract (m89/m97/m120):
//   a-frag: A[m][k], m=lane&15, k=(lane>>4)*8+j
//   b-frag: B[k][n], n=lane&15, k=(lane>>4)*8+j
//   d:      D[m][n], n(col)=lane&15, m(row)=(lane>>4)*4+reg

typedef unsigned short u16;
typedef unsigned int u32;
typedef __attribute__((ext_vector_type(8))) short bf16x8;
typedef __attribute__((ext_vector_type(4))) float f32x4;
typedef __attribute__((ext_vector_type(4))) u32 u32x4;
typedef const __attribute__((address_space(1))) u16* gas1;
typedef __attribute__((address_space(3))) u16* las3;

#define NN 2048
#define EE 64
#define CC 128
#define BB 32

__device__ __forceinline__ u16 f2bf(float f) {
  u32 u = __builtin_bit_cast(u32, f);
  u += 0x7fffu + ((u >> 16) & 1u);   // round-to-nearest-even
  return (u16)(u >> 16);
}

__device__ __forceinline__ f32x4 mfma16(bf16x8 a, bf16x8 b, f32x4 c) {
  return __builtin_amdgcn_mfma_f32_16x16x32_bf16(a, b, c, 0, 0, 0);
}

// ---------------- mega0: prep(512) + poolt(256) + xtrans(1024), block-ranged
__global__ __launch_bounds__(256) void k_mega0(
    const float* __restrict__ x, const float* __restrict__ ne,
    const float* __restrict__ te, const float* __restrict__ pool,
    const float* __restrict__ bias_pool, const float* __restrict__ lnw,
    const float* __restrict__ lnb,
    float* __restrict__ e, u16* __restrict__ e_bf, float* __restrict__ bias_out,
    u16* __restrict__ pool_r, u16* __restrict__ x_t, u16* __restrict__ xg_t) {
  __shared__ __align__(16) char smem[34048];
  int bid = blockIdx.x;
  int tid = threadIdx.x;
  if (bid < 512) {
    // ---- prep: 4 nodes/block, one wave per node
    float* sh = (float*)smem;             // [4][64]
    int nw = tid >> 6, d = tid & 63;
    int n = bid * 4 + nw;
    float v = ne[n * EE + d] + te[d];
    float s = v;
#pragma unroll
    for (int off = 32; off > 0; off >>= 1) s += __shfl_xor(s, off);
    float mean = s * (1.0f / 64.0f);
    float c = v - mean;
    float q = c * c;
#pragma unroll
    for (int off = 32; off > 0; off >>= 1) q += __shfl_xor(q, off);
    float inv = rsqrtf(q * (1.0f / 64.0f) + 1e-12f);
    float ev = c * inv * lnw[d] + lnb[d];
    e[n * EE + d] = ev;
    e_bf[n * EE + d] = f2bf(ev);
    sh[nw * 64 + d] = ev;
    __syncthreads();
#pragma unroll
    for (int oo = 0; oo < 2; ++oo) {
      int o = oo * 64 + d;
      float acc = 0.f;
#pragma unroll 8
      for (int dd = 0; dd < 64; ++dd) acc += sh[nw * 64 + dd] * bias_pool[dd * CC + o];
      bias_out[n * CC + o] = acc;
    }
  } else if (bid < 768) {
    // ---- poolt: pool [d][ki][o] fp32 -> pool_r [(o,ki)][d] bf16
    float* t = (float*)smem;              // [128][65]
    int ki = bid - 512;
    for (int it = 0; it < 32; ++it) {
      int idx = it * 256 + tid;
      int d = idx >> 7, o = idx & 127;
      t[o * 65 + d] = pool[d * 32768 + ki * 128 + o];
    }
    __syncthreads();
    for (int it = 0; it < 32; ++it) {
      int idx = it * 256 + tid;
      int o = idx >> 6, d = idx & 63;
      __builtin_nontemporal_store(f2bf(t[o * 65 + d]),
                                  &pool_r[((size_t)o * 256 + ki) * 64 + d]);
    }
  } else {
    // ---- xtrans (R13 two-pass): x -> x_t [b][c][m] bf16 and
    // xg_t [m][b][0..128) bf16.
    u16* t = (u16*)smem;                  // [128][68]
    int bx = bid - 768;
    int b = bx >> 5;
    int m0 = (bx & 31) * 64;
    for (int it = 0; it < 32; ++it) {
      int idx = it * 256 + tid;
      int m = idx >> 7, c = idx & 127;
      float v = x[((size_t)b * NN + m0 + m) * CC + c];
      t[c * 68 + m] = f2bf(v);
    }
    __syncthreads();
    for (int it = 0; it < 32; ++it) {
      int idx = it * 256 + tid;
      int c = idx >> 6, m = idx & 63;
      __builtin_nontemporal_store(t[c * 68 + m],
                                  &x_t[((size_t)b * CC + c) * NN + m0 + m]);
    }
    for (int it = 0; it < 16; ++it) {
      int idx = it * 256 + tid;
      int m = idx >> 6, c2 = idx & 63;
      float2 v = *(const float2*)&x[((size_t)b * NN + m0 + m) * CC + c2 * 2];
      u32 pk = (u32)f2bf(v.x) | ((u32)f2bf(v.y) << 16);
      __builtin_nontemporal_store(pk,
          (u32*)&xg_t[(((size_t)(m0 + m)) * 32 + b) * 256 + c2 * 2]);
    }
  }
}

// ---------------- k_Sexp: P = exp(e @ e^T) bf16 + atomic row sums.
// 64x64 tile (35KB LDS -> 4 blk/CU), 4x4 per thread, no max-sub (|S|<=64).
__global__ __launch_bounds__(256) void k_Sexp(const float* __restrict__ e,
                                              u16* __restrict__ P,
                                              float* __restrict__ rs) {
  __shared__ float er[64 * 68];
  __shared__ float ec[64 * 68];
  int n0 = (blockIdx.x >> 5) * 64, m0 = (blockIdx.x & 31) * 64;
  int tid = threadIdx.x;
  for (int it = 0; it < 16; ++it) {
    int idx = it * 256 + tid;
    int r = idx >> 6, d = idx & 63;
    er[r * 68 + d] = e[(n0 + r) * EE + d];
    ec[r * 68 + d] = e[(m0 + r) * EE + d];
  }
  __syncthreads();
  int tx = tid & 15, ty = tid >> 4;
  float acc[4][4] = {};
  for (int d4 = 0; d4 < 64; d4 += 4) {
    f32x4 av[4], bv[4];
#pragma unroll
    for (int i = 0; i < 4; ++i) av[i] = *(const f32x4*)&er[(ty + 16 * i) * 68 + d4];
#pragma unroll
    for (int j = 0; j < 4; ++j) bv[j] = *(const f32x4*)&ec[(tx + 16 * j) * 68 + d4];
#pragma unroll
    for (int i = 0; i < 4; ++i)
#pragma unroll
      for (int j = 0; j < 4; ++j) {
        acc[i][j] += av[i][0] * bv[j][0];
        acc[i][j] += av[i][1] * bv[j][1];
        acc[i][j] += av[i][2] * bv[j][2];
        acc[i][j] += av[i][3] * bv[j][3];
      }
  }
#pragma unroll
  for (int i = 0; i < 4; ++i) {
    float s = 0.f;
#pragma unroll
    for (int j = 0; j < 4; ++j) {
      float pv = __expf(acc[i][j]);
      P[(size_t)(n0 + ty + 16 * i) * NN + m0 + tx + 16 * j] = f2bf(pv);
      s += pv;
    }
#pragma unroll
    for (int off = 8; off > 0; off >>= 1) s += __shfl_xor(s, off);  // reduce over tx
    if (tx == 0) atomicAdd(&rs[n0 + ty + 16 * i], s);
  }
}

// ---------------- mega2: aggr(512 blocks, first) + gen(4096 blocks), block-ranged
__global__ __launch_bounds__(256, 4) void k_mega2(
    const u16* __restrict__ P, const u16* __restrict__ x_t,
    const float* __restrict__ rs, u16* __restrict__ xg_t,
    const u16* __restrict__ e_bf, const u16* __restrict__ pool_r,
    u16* __restrict__ W_p) {
  __shared__ __align__(16) char smem[34048];
  int tid = threadIdx.x;
  int lane = tid & 63, w = tid >> 6;
  int lm = lane & 15, lq = lane >> 4;
  if (blockIdx.x < 512) {
    // ---- aggr (R13-identical + nt xg stores): XOR-swizzled staging+reads,
    // mb%8 XCD pin.
    u16* As = (u16*)smem;               // [128][64] linear dest (global_load_lds)
    u16* Bs = (u16*)(smem + 16384);
    int mb = blockIdx.x & 15, b = blockIdx.x >> 4;
    int n0 = mb * 128;
    int wm = w >> 1, wn = w & 1;
    f32x4 acc[4][4] = {};
    const u16* a_src = P + (size_t)n0 * NN;
    const u16* b_src = x_t + (size_t)b * CC * NN;
    for (int kc = 0; kc < NN; kc += 64) {
      __syncthreads();
#pragma unroll
      for (int ii = 0; ii < 4; ++ii) {
        int idx = ii * 256 + tid;
        int row = idx >> 3, ch = idx & 7;
        int sc = kc + ((ch ^ (row & 7)) << 3);   // pre-swizzled source col
        __builtin_amdgcn_global_load_lds((gas1)(a_src + (size_t)row * NN + sc),
                                         (las3)(As + (size_t)(ii * 256 + w * 64) * 8), 16, 0, 0);
        __builtin_amdgcn_global_load_lds((gas1)(b_src + (size_t)row * NN + sc),
                                         (las3)(Bs + (size_t)(ii * 256 + w * 64) * 8), 16, 0, 0);
      }
      __syncthreads();
#pragma unroll
      for (int kk = 0; kk < 64; kk += 32) {
        int cb = (kk >> 3) + lq;                 // 16B chunk index (unswizzled)
        bf16x8 af[4], bq[4];
#pragma unroll
        for (int i = 0; i < 4; ++i) {
          int row = wm * 64 + i * 16 + lm;
          af[i] = *(const bf16x8*)&As[row * 64 + ((cb ^ (row & 7)) << 3)];
        }
#pragma unroll
        for (int j = 0; j < 4; ++j) {
          int row = wn * 64 + j * 16 + lm;
          bq[j] = *(const bf16x8*)&Bs[row * 64 + ((cb ^ (row & 7)) << 3)];
        }
#pragma unroll
        for (int i = 0; i < 4; ++i)
#pragma unroll
          for (int j = 0; j < 4; ++j)
            acc[i][j] = mfma16(af[i], bq[j], acc[i][j]);
      }
    }
#pragma unroll
    for (int i = 0; i < 4; ++i) {
      int nr = n0 + wm * 64 + i * 16 + lq * 4;
#pragma unroll
      for (int r = 0; r < 4; ++r) {
        float sc = 1.0f / rs[nr + r];
#pragma unroll
        for (int j = 0; j < 4; ++j) {
          int c = wn * 64 + j * 16 + lm;
          __builtin_nontemporal_store(f2bf(acc[i][j][r] * sc),
              &xg_t[((size_t)(nr + r) * 32 + b) * 256 + 128 + c]);
        }
      }
    }
  } else {
    // ---- gen v3: 2 o x 32 nodes x 256 ki; g = nb*64 + og -> XCD = og%8
    // (o-pin: 16 o = 512KB pool_r per XCD, L2-resident, R13 invariant).
    // Wave w: o_l = w&1, ki-half = w>>1. LDS Tl[2o][32n][264ki-pad],
    // o-stride 8456 u16. Store per (n,ks): [2o][32ki] = 128B full line, nt.
    u16* Tl = (u16*)smem;
    int g = blockIdx.x - 512;
    int og = g & 63, nb = g >> 6;
    int o0 = og * 2, n0 = nb * 32;
    int o_l = w & 1, kih = w >> 1;
    bf16x8 eB[2][2];
#pragma unroll
    for (int nt = 0; nt < 2; ++nt)
#pragma unroll
      for (int ks = 0; ks < 2; ++ks)
        eB[nt][ks] = *(const bf16x8*)&e_bf[(n0 + nt * 16 + lm) * EE + ks * 32 + lq * 8];
    const u16* pbase = pool_r + ((size_t)(o0 + o_l) * 256 + kih * 128) * 64;
#pragma unroll
    for (int ct = 0; ct < 8; ++ct) {
      const u16* ap = pbase + (ct * 16 + lm) * 64 + lq * 8;
      bf16x8 pA0 = *(const bf16x8*)ap;          // d = lq*8..
      bf16x8 pA1 = *(const bf16x8*)(ap + 32);   // d = 32+lq*8..
#pragma unroll
      for (int nt = 0; nt < 2; ++nt) {
        f32x4 gv = {0.f, 0.f, 0.f, 0.f};
        gv = mfma16(pA0, eB[nt][0], gv);
        gv = mfma16(pA1, eB[nt][1], gv);
        // D: node = lm (col), ki = kih*128 + ct*16 + lq*4 + r (row)
        ushort4 h;
        h.x = f2bf(gv[0]); h.y = f2bf(gv[1]); h.z = f2bf(gv[2]); h.w = f2bf(gv[3]);
        *(ushort4*)&Tl[o_l * 8456 + (nt * 16 + lm) * 264 + kih * 128 + ct * 16 + lq * 4] = h;
      }
    }
    __syncthreads();
    // store: W_p[n][ks][o][ki%32]; per wave: one n, 8 ks-lines of 128B, nt.
#pragma unroll
    for (int it = 0; it < 8; ++it) {
      int idx = it * 256 + tid;
      int n = idx >> 6, rem = idx & 63;
      int ks = rem >> 3, rem2 = rem & 7;
      int o = rem2 >> 2, ki8 = rem2 & 3;
      u32x4 v = *(const u32x4*)&Tl[o * 8456 + n * 264 + ks * 32 + ki8 * 8];
      __builtin_nontemporal_store(v,
          (u32x4*)&W_p[(size_t)(n0 + n) * 32768 + ks * 4096 + (o0 + o) * 32 + ki8 * 8]);
    }
  }
}

// ---------------- k_apply v2: out[b,n,o] = xg[n] @ W[n] + bias.
// W_p permuted layout -> B-frag load = fully-coalesced 1KB/wave, nt (stream
// once, don't pollute L2); out stores nt.
__global__ __launch_bounds__(256, 3) void k_apply(const u16* __restrict__ xg_t,
                                                  const u16* __restrict__ W_p,
                                                  const float* __restrict__ bias,
                                                  float* __restrict__ out) {
  int n0 = blockIdx.x * 2;
  int tid = threadIdx.x;
  int lane = tid & 63, w = tid >> 6;
  int lm = lane & 15, lq = lane >> 4;
  int n = n0 + (w & 1), oh = w >> 1;    // node, o-half(64)
  const u16* xb = xg_t + (size_t)n * 32 * 256;
  const u16* wb = W_p + (size_t)n * 32768 + (size_t)oh * 64 * 32;
  f32x4 acc[2][4] = {};
#pragma unroll
  for (int ks = 0; ks < 8; ++ks) {
    int ko = ks * 32 + lq * 8;
    bf16x8 a0 = *(const bf16x8*)&xb[lm * 256 + ko];
    bf16x8 a1 = *(const bf16x8*)&xb[(16 + lm) * 256 + ko];
#pragma unroll
    for (int ot = 0; ot < 4; ++ot) {
      bf16x8 bv = __builtin_nontemporal_load(
          (const bf16x8*)&wb[(size_t)ks * 4096 + (ot * 16 + lm) * 32 + lq * 8]);
      acc[0][ot] = mfma16(a0, bv, acc[0][ot]);
      acc[1][ot] = mfma16(a1, bv, acc[1][ot]);
    }
  }
#pragma unroll
  for (int ot = 0; ot < 4; ++ot) {
    int oc = oh * 64 + ot * 16 + lm;
    float bv = bias[n * CC + oc];
#pragma unroll
    for (int mt = 0; mt < 2; ++mt)
#pragma unroll
      for (int r = 0; r < 4; ++r) {
        int b = mt * 16 + lq * 4 + r;
        __builtin_nontemporal_store(acc[mt][ot][r] + bv,
                                    &out[((size_t)b * NN + n) * CC + oc]);
      }
  }
}

extern "C" void kernel_launch(void* const* d_in, const int* in_sizes, int n_in,
                              void* d_out, int out_size, void* d_ws, size_t ws_size,
                              hipStream_t stream) {
  const float* x        = (const float*)d_in[0];
  const float* node_emb = (const float*)d_in[1];
  const float* time_emb = (const float*)d_in[2];
  const float* pool     = (const float*)d_in[3];
  const float* bias_pl  = (const float*)d_in[4];
  const float* ln_w     = (const float*)d_in[5];
  const float* ln_b     = (const float*)d_in[6];
  float* out = (float*)d_out;

  char* p = (char*)d_ws;
  auto alloc = [&](size_t bytes) {
    char* r = p;
    p += (bytes + 255) & ~(size_t)255;
    return r;
  };
  float* e      = (float*)alloc((size_t)NN * EE * 4);
  u16*   e_bf   = (u16*)  alloc((size_t)NN * EE * 2);
  float* biasb  = (float*)alloc((size_t)NN * CC * 4);
  u16*   Pm     = (u16*)  alloc((size_t)NN * NN * 2);          // exp(S), unnormalized
  float* rs     = (float*)alloc((size_t)NN * 4);               // row sums
  u16*   x_t    = (u16*)  alloc((size_t)BB * CC * NN * 2);
  u16*   xg_t   = (u16*)  alloc((size_t)NN * BB * 256 * 2);    // [node][batch][x||xagg]
  u16*   pool_r = (u16*)  alloc((size_t)128 * 256 * 64 * 2);
  u16*   W_p    = (u16*)  alloc((size_t)NN * 32768 * 2);       // 128 MB, permuted

  if (ws_size < (size_t)(p - (char*)d_ws)) return;

  (void)hipMemsetAsync(rs, 0, (size_t)NN * 4, stream);

  k_mega0<<<1792, 256, 0, stream>>>(x, node_emb, time_emb, pool, bias_pl, ln_w, ln_b,
                                    e, e_bf, biasb, pool_r, x_t, xg_t);
  k_Sexp<<<1024, 256, 0, stream>>>(e, Pm, rs);
  k_mega2<<<4608, 256, 0, stream>>>(Pm, x_t, rs, xg_t, e_bf, pool_r, W_p);
  k_apply<<<NN / 2, 256, 0, stream>>>(xg_t, W_p, biasb, out);
}

// Round 11
// 231.213 us; speedup vs baseline: 1.1131x; 1.0809x over previous
//
#include <hip/hip_runtime.h>

// GCN_77584289234976 — round 18.
// R17 post-mortem: nt stores FALSIFIED — mega2 74.7->90.4 (+16us): nt broke
// L2 write-coalescing of aggr's scalar 2B xg stores and pushed W_p/xg_t out
// of L3 (apply re-read from HBM). xtrans-fusion confirmed as R16's +23us.
// R18 = best-known config (R13 + gen v3 + two-pass xtrans, ALL plain
// stores) + one new fix: k_apply epilogue staged through LDS so out is
// written as 64 rows x 512B contiguous float4 bursts (was 64B half-lines
// at 1MB b-stride -> line-fill reads + poor write efficiency).
// MFMA 16x16x32 bf16 layout contract (m89/m97/m120):
//   a-frag: A[m][k], m=lane&15, k=(lane>>4)*8+j
//   b-frag: B[k][n], n=lane&15, k=(lane>>4)*8+j
//   d:      D[m][n], n(col)=lane&15, m(row)=(lane>>4)*4+reg

typedef unsigned short u16;
typedef unsigned int u32;
typedef __attribute__((ext_vector_type(8))) short bf16x8;
typedef __attribute__((ext_vector_type(4))) float f32x4;
typedef const __attribute__((address_space(1))) u16* gas1;
typedef __attribute__((address_space(3))) u16* las3;

#define NN 2048
#define EE 64
#define CC 128
#define BB 32

__device__ __forceinline__ u16 f2bf(float f) {
  u32 u = __builtin_bit_cast(u32, f);
  u += 0x7fffu + ((u >> 16) & 1u);   // round-to-nearest-even
  return (u16)(u >> 16);
}

__device__ __forceinline__ f32x4 mfma16(bf16x8 a, bf16x8 b, f32x4 c) {
  return __builtin_amdgcn_mfma_f32_16x16x32_bf16(a, b, c, 0, 0, 0);
}

// ---------------- mega0: prep(512) + poolt(256) + xtrans(1024), block-ranged
__global__ __launch_bounds__(256) void k_mega0(
    const float* __restrict__ x, const float* __restrict__ ne,
    const float* __restrict__ te, const float* __restrict__ pool,
    const float* __restrict__ bias_pool, const float* __restrict__ lnw,
    const float* __restrict__ lnb,
    float* __restrict__ e, u16* __restrict__ e_bf, float* __restrict__ bias_out,
    u16* __restrict__ pool_r, u16* __restrict__ x_t, u16* __restrict__ xg_t) {
  __shared__ __align__(16) char smem[34048];
  int bid = blockIdx.x;
  int tid = threadIdx.x;
  if (bid < 512) {
    // ---- prep: 4 nodes/block, one wave per node
    float* sh = (float*)smem;             // [4][64]
    int nw = tid >> 6, d = tid & 63;
    int n = bid * 4 + nw;
    float v = ne[n * EE + d] + te[d];
    float s = v;
#pragma unroll
    for (int off = 32; off > 0; off >>= 1) s += __shfl_xor(s, off);
    float mean = s * (1.0f / 64.0f);
    float c = v - mean;
    float q = c * c;
#pragma unroll
    for (int off = 32; off > 0; off >>= 1) q += __shfl_xor(q, off);
    float inv = rsqrtf(q * (1.0f / 64.0f) + 1e-12f);
    float ev = c * inv * lnw[d] + lnb[d];
    e[n * EE + d] = ev;
    e_bf[n * EE + d] = f2bf(ev);
    sh[nw * 64 + d] = ev;
    __syncthreads();
#pragma unroll
    for (int oo = 0; oo < 2; ++oo) {
      int o = oo * 64 + d;
      float acc = 0.f;
#pragma unroll 8
      for (int dd = 0; dd < 64; ++dd) acc += sh[nw * 64 + dd] * bias_pool[dd * CC + o];
      bias_out[n * CC + o] = acc;
    }
  } else if (bid < 768) {
    // ---- poolt: pool [d][ki][o] fp32 -> pool_r [(o,ki)][d] bf16
    float* t = (float*)smem;              // [128][65]
    int ki = bid - 512;
    for (int it = 0; it < 32; ++it) {
      int idx = it * 256 + tid;
      int d = idx >> 7, o = idx & 127;
      t[o * 65 + d] = pool[d * 32768 + ki * 128 + o];
    }
    __syncthreads();
    for (int it = 0; it < 32; ++it) {
      int idx = it * 256 + tid;
      int o = idx >> 6, d = idx & 63;
      pool_r[((size_t)o * 256 + ki) * 64 + d] = f2bf(t[o * 65 + d]);
    }
  } else {
    // ---- xtrans (two-pass): x -> x_t [b][c][m] bf16, xg_t [m][b][0..128)
    u16* t = (u16*)smem;                  // [128][68]
    int bx = bid - 768;
    int b = bx >> 5;
    int m0 = (bx & 31) * 64;
    for (int it = 0; it < 32; ++it) {
      int idx = it * 256 + tid;
      int m = idx >> 7, c = idx & 127;
      float v = x[((size_t)b * NN + m0 + m) * CC + c];
      t[c * 68 + m] = f2bf(v);
    }
    __syncthreads();
    for (int it = 0; it < 32; ++it) {
      int idx = it * 256 + tid;
      int c = idx >> 6, m = idx & 63;
      x_t[((size_t)b * CC + c) * NN + m0 + m] = t[c * 68 + m];
    }
    for (int it = 0; it < 16; ++it) {
      int idx = it * 256 + tid;
      int m = idx >> 6, c2 = idx & 63;
      float2 v = *(const float2*)&x[((size_t)b * NN + m0 + m) * CC + c2 * 2];
      u32 pk = (u32)f2bf(v.x) | ((u32)f2bf(v.y) << 16);
      *(u32*)&xg_t[(((size_t)(m0 + m)) * 32 + b) * 256 + c2 * 2] = pk;
    }
  }
}

// ---------------- k_Sexp: P = exp(e @ e^T) bf16 + atomic row sums.
// 64x64 tile (35KB LDS -> 4 blk/CU), 4x4 per thread, no max-sub (|S|<=64).
__global__ __launch_bounds__(256) void k_Sexp(const float* __restrict__ e,
                                              u16* __restrict__ P,
                                              float* __restrict__ rs) {
  __shared__ float er[64 * 68];
  __shared__ float ec[64 * 68];
  int n0 = (blockIdx.x >> 5) * 64, m0 = (blockIdx.x & 31) * 64;
  int tid = threadIdx.x;
  for (int it = 0; it < 16; ++it) {
    int idx = it * 256 + tid;
    int r = idx >> 6, d = idx & 63;
    er[r * 68 + d] = e[(n0 + r) * EE + d];
    ec[r * 68 + d] = e[(m0 + r) * EE + d];
  }
  __syncthreads();
  int tx = tid & 15, ty = tid >> 4;
  float acc[4][4] = {};
  for (int d4 = 0; d4 < 64; d4 += 4) {
    f32x4 av[4], bv[4];
#pragma unroll
    for (int i = 0; i < 4; ++i) av[i] = *(const f32x4*)&er[(ty + 16 * i) * 68 + d4];
#pragma unroll
    for (int j = 0; j < 4; ++j) bv[j] = *(const f32x4*)&ec[(tx + 16 * j) * 68 + d4];
#pragma unroll
    for (int i = 0; i < 4; ++i)
#pragma unroll
      for (int j = 0; j < 4; ++j) {
        acc[i][j] += av[i][0] * bv[j][0];
        acc[i][j] += av[i][1] * bv[j][1];
        acc[i][j] += av[i][2] * bv[j][2];
        acc[i][j] += av[i][3] * bv[j][3];
      }
  }
#pragma unroll
  for (int i = 0; i < 4; ++i) {
    float s = 0.f;
#pragma unroll
    for (int j = 0; j < 4; ++j) {
      float pv = __expf(acc[i][j]);
      P[(size_t)(n0 + ty + 16 * i) * NN + m0 + tx + 16 * j] = f2bf(pv);
      s += pv;
    }
#pragma unroll
    for (int off = 8; off > 0; off >>= 1) s += __shfl_xor(s, off);  // reduce over tx
    if (tx == 0) atomicAdd(&rs[n0 + ty + 16 * i], s);
  }
}

// ---------------- mega2: aggr(512 blocks, first) + gen(4096 blocks), block-ranged
__global__ __launch_bounds__(256, 4) void k_mega2(
    const u16* __restrict__ P, const u16* __restrict__ x_t,
    const float* __restrict__ rs, u16* __restrict__ xg_t,
    const u16* __restrict__ e_bf, const u16* __restrict__ pool_r,
    u16* __restrict__ W_p) {
  __shared__ __align__(16) char smem[34048];
  int tid = threadIdx.x;
  int lane = tid & 63, w = tid >> 6;
  int lm = lane & 15, lq = lane >> 4;
  if (blockIdx.x < 512) {
    // ---- aggr (R13-identical): XOR-swizzled staging+reads, mb%8 XCD pin.
    u16* As = (u16*)smem;               // [128][64] linear dest (global_load_lds)
    u16* Bs = (u16*)(smem + 16384);
    int mb = blockIdx.x & 15, b = blockIdx.x >> 4;
    int n0 = mb * 128;
    int wm = w >> 1, wn = w & 1;
    f32x4 acc[4][4] = {};
    const u16* a_src = P + (size_t)n0 * NN;
    const u16* b_src = x_t + (size_t)b * CC * NN;
    for (int kc = 0; kc < NN; kc += 64) {
      __syncthreads();
#pragma unroll
      for (int ii = 0; ii < 4; ++ii) {
        int idx = ii * 256 + tid;
        int row = idx >> 3, ch = idx & 7;
        int sc = kc + ((ch ^ (row & 7)) << 3);   // pre-swizzled source col
        __builtin_amdgcn_global_load_lds((gas1)(a_src + (size_t)row * NN + sc),
                                         (las3)(As + (size_t)(ii * 256 + w * 64) * 8), 16, 0, 0);
        __builtin_amdgcn_global_load_lds((gas1)(b_src + (size_t)row * NN + sc),
                                         (las3)(Bs + (size_t)(ii * 256 + w * 64) * 8), 16, 0, 0);
      }
      __syncthreads();
#pragma unroll
      for (int kk = 0; kk < 64; kk += 32) {
        int cb = (kk >> 3) + lq;                 // 16B chunk index (unswizzled)
        bf16x8 af[4], bq[4];
#pragma unroll
        for (int i = 0; i < 4; ++i) {
          int row = wm * 64 + i * 16 + lm;
          af[i] = *(const bf16x8*)&As[row * 64 + ((cb ^ (row & 7)) << 3)];
        }
#pragma unroll
        for (int j = 0; j < 4; ++j) {
          int row = wn * 64 + j * 16 + lm;
          bq[j] = *(const bf16x8*)&Bs[row * 64 + ((cb ^ (row & 7)) << 3)];
        }
#pragma unroll
        for (int i = 0; i < 4; ++i)
#pragma unroll
          for (int j = 0; j < 4; ++j)
            acc[i][j] = mfma16(af[i], bq[j], acc[i][j]);
      }
    }
#pragma unroll
    for (int i = 0; i < 4; ++i) {
      int nr = n0 + wm * 64 + i * 16 + lq * 4;
#pragma unroll
      for (int r = 0; r < 4; ++r) {
        float sc = 1.0f / rs[nr + r];
#pragma unroll
        for (int j = 0; j < 4; ++j) {
          int c = wn * 64 + j * 16 + lm;
          xg_t[((size_t)(nr + r) * 32 + b) * 256 + 128 + c] = f2bf(acc[i][j][r] * sc);
        }
      }
    }
  } else {
    // ---- gen v3: 2 o x 32 nodes x 256 ki; g = nb*64 + og -> XCD = og%8
    // (o-pin: 16 o = 512KB pool_r per XCD, L2-resident, R13 invariant).
    // Wave w: o_l = w&1, ki-half = w>>1. LDS Tl[2o][32n][264ki-pad],
    // o-stride 8456 u16. Store per (n,ks): [2o][32ki] = 128B full line.
    u16* Tl = (u16*)smem;
    int g = blockIdx.x - 512;
    int og = g & 63, nb = g >> 6;
    int o0 = og * 2, n0 = nb * 32;
    int o_l = w & 1, kih = w >> 1;
    bf16x8 eB[2][2];
#pragma unroll
    for (int nt = 0; nt < 2; ++nt)
#pragma unroll
      for (int ks = 0; ks < 2; ++ks)
        eB[nt][ks] = *(const bf16x8*)&e_bf[(n0 + nt * 16 + lm) * EE + ks * 32 + lq * 8];
    const u16* pbase = pool_r + ((size_t)(o0 + o_l) * 256 + kih * 128) * 64;
#pragma unroll
    for (int ct = 0; ct < 8; ++ct) {
      const u16* ap = pbase + (ct * 16 + lm) * 64 + lq * 8;
      bf16x8 pA0 = *(const bf16x8*)ap;          // d = lq*8..
      bf16x8 pA1 = *(const bf16x8*)(ap + 32);   // d = 32+lq*8..
#pragma unroll
      for (int nt = 0; nt < 2; ++nt) {
        f32x4 gv = {0.f, 0.f, 0.f, 0.f};
        gv = mfma16(pA0, eB[nt][0], gv);
        gv = mfma16(pA1, eB[nt][1], gv);
        // D: node = lm (col), ki = kih*128 + ct*16 + lq*4 + r (row)
        ushort4 h;
        h.x = f2bf(gv[0]); h.y = f2bf(gv[1]); h.z = f2bf(gv[2]); h.w = f2bf(gv[3]);
        *(ushort4*)&Tl[o_l * 8456 + (nt * 16 + lm) * 264 + kih * 128 + ct * 16 + lq * 4] = h;
      }
    }
    __syncthreads();
    // store: W_p[n][ks][o][ki%32]; per wave: one n, 8 ks-lines of 128B.
#pragma unroll
    for (int it = 0; it < 8; ++it) {
      int idx = it * 256 + tid;
      int n = idx >> 6, rem = idx & 63;
      int ks = rem >> 3, rem2 = rem & 7;
      int o = rem2 >> 2, ki8 = rem2 & 3;
      uint4 v = *(const uint4*)&Tl[o * 8456 + n * 264 + ks * 32 + ki8 * 8];
      *(uint4*)&W_p[(size_t)(n0 + n) * 32768 + ks * 4096 + (o0 + o) * 32 + ki8 * 8] = v;
    }
  }
}

// ---------------- k_apply v3: out[b,n,o] = xg[n] @ W[n] + bias.
// W_p permuted -> B-frag loads fully-coalesced 1KB/wave. Epilogue staged
// through LDS: out written as 64 rows x 512B contiguous float4 bursts
// (was 64B half-lines at 1MB b-stride).
__global__ __launch_bounds__(256, 3) void k_apply(const u16* __restrict__ xg_t,
                                                  const u16* __restrict__ W_p,
                                                  const float* __restrict__ bias,
                                                  float* __restrict__ out) {
  __shared__ float L[2 * 32 * 132];     // 33792 B
  int n0 = blockIdx.x * 2;
  int tid = threadIdx.x;
  int lane = tid & 63, w = tid >> 6;
  int lm = lane & 15, lq = lane >> 4;
  int n = n0 + (w & 1), oh = w >> 1;    // node, o-half(64)
  const u16* xb = xg_t + (size_t)n * 32 * 256;
  const u16* wb = W_p + (size_t)n * 32768 + (size_t)oh * 64 * 32;
  f32x4 acc[2][4] = {};
#pragma unroll
  for (int ks = 0; ks < 8; ++ks) {
    int ko = ks * 32 + lq * 8;
    bf16x8 a0 = *(const bf16x8*)&xb[lm * 256 + ko];
    bf16x8 a1 = *(const bf16x8*)&xb[(16 + lm) * 256 + ko];
#pragma unroll
    for (int ot = 0; ot < 4; ++ot) {
      bf16x8 bv = *(const bf16x8*)&wb[(size_t)ks * 4096 + (ot * 16 + lm) * 32 + lq * 8];
      acc[0][ot] = mfma16(a0, bv, acc[0][ot]);
      acc[1][ot] = mfma16(a1, bv, acc[1][ot]);
    }
  }
  // stage acc to LDS: L[nl][b][oc], oc-stride padless rows of 132
#pragma unroll
  for (int ot = 0; ot < 4; ++ot) {
    int oc = oh * 64 + ot * 16 + lm;
#pragma unroll
    for (int mt = 0; mt < 2; ++mt)
#pragma unroll
      for (int r = 0; r < 4; ++r) {
        int b = mt * 16 + lq * 4 + r;
        L[((w & 1) * 32 + b) * 132 + oc] = acc[mt][ot][r];
      }
  }
  __syncthreads();
  // write phase: 64 rows (2n x 32b) x 128 floats; 32 threads per row ->
  // 512B contiguous burst per row.
#pragma unroll
  for (int it = 0; it < 8; ++it) {
    int idx = it * 256 + tid;
    int row = idx >> 5, seg = idx & 31;
    int nl = row >> 5, b = row & 31;
    float4 v = *(const float4*)&L[(nl * 32 + b) * 132 + seg * 4];
    float4 bv = *(const float4*)&bias[(n0 + nl) * CC + seg * 4];
    float4 o4;
    o4.x = v.x + bv.x; o4.y = v.y + bv.y; o4.z = v.z + bv.z; o4.w = v.w + bv.w;
    *(float4*)&out[((size_t)b * NN + n0 + nl) * CC + seg * 4] = o4;
  }
}

extern "C" void kernel_launch(void* const* d_in, const int* in_sizes, int n_in,
                              void* d_out, int out_size, void* d_ws, size_t ws_size,
                              hipStream_t stream) {
  const float* x        = (const float*)d_in[0];
  const float* node_emb = (const float*)d_in[1];
  const float* time_emb = (const float*)d_in[2];
  const float* pool     = (const float*)d_in[3];
  const float* bias_pl  = (const float*)d_in[4];
  const float* ln_w     = (const float*)d_in[5];
  const float* ln_b     = (const float*)d_in[6];
  float* out = (float*)d_out;

  char* p = (char*)d_ws;
  auto alloc = [&](size_t bytes) {
    char* r = p;
    p += (bytes + 255) & ~(size_t)255;
    return r;
  };
  float* e      = (float*)alloc((size_t)NN * EE * 4);
  u16*   e_bf   = (u16*)  alloc((size_t)NN * EE * 2);
  float* biasb  = (float*)alloc((size_t)NN * CC * 4);
  u16*   Pm     = (u16*)  alloc((size_t)NN * NN * 2);          // exp(S), unnormalized
  float* rs     = (float*)alloc((size_t)NN * 4);               // row sums
  u16*   x_t    = (u16*)  alloc((size_t)BB * CC * NN * 2);
  u16*   xg_t   = (u16*)  alloc((size_t)NN * BB * 256 * 2);    // [node][batch][x||xagg]
  u16*   pool_r = (u16*)  alloc((size_t)128 * 256 * 64 * 2);
  u16*   W_p    = (u16*)  alloc((size_t)NN * 32768 * 2);       // 128 MB, permuted

  if (ws_size < (size_t)(p - (char*)d_ws)) return;

  (void)hipMemsetAsync(rs, 0, (size_t)NN * 4, stream);

  k_mega0<<<1792, 256, 0, stream>>>(x, node_emb, time_emb, pool, bias_pl, ln_w, ln_b,
                                    e, e_bf, biasb, pool_r, x_t, xg_t);
  k_Sexp<<<1024, 256, 0, stream>>>(e, Pm, rs);
  k_mega2<<<4608, 256, 0, stream>>>(Pm, x_t, rs, xg_t, e_bf, pool_r, W_p);
  k_apply<<<NN / 2, 256, 0, stream>>>(xg_t, W_p, biasb, out);
}